// Round 4
// baseline (111.547 us; speedup 1.0000x reference)
//
#include <hip/hip_runtime.h>
#include <math.h>

#define NB 8192
#define DK 256
#define BM 128
#define NTILE 64                    // NB/BM
#define NBLK (NTILE*(NTILE+1)/2)    // 2080 upper-triangular tiles
#define GRID 512                    // blocks; each owns ~4 consecutive tiles

typedef __bf16 bf16x8 __attribute__((ext_vector_type(8)));
typedef float f32x4 __attribute__((ext_vector_type(4)));

__device__ inline unsigned short f2bf(float f) {
  unsigned u = __float_as_uint(f);
  u += 0x7fffu + ((u >> 16) & 1u);          // round-to-nearest-even
  return (unsigned short)(u >> 16);
}

__device__ inline void gld_lds16(const void* g, void* l) {
  __builtin_amdgcn_global_load_lds(
      (const __attribute__((address_space(1))) void*)g,
      (__attribute__((address_space(3))) void*)l, 16, 0, 0);
}

// ---------------- Kernel 1: L2-normalize rows, fp32 -> bf16
__global__ __launch_bounds__(256) void normalize_kernel(
    const float* __restrict__ emb, unsigned short* __restrict__ ebf) {
  int wave = threadIdx.x >> 6;
  int lane = threadIdx.x & 63;
  int row = blockIdx.x * 4 + wave;                  // one wave per row
  const float4* src = reinterpret_cast<const float4*>(emb + (size_t)row * DK) + lane;
  float4 v = *src;
  float ss = v.x * v.x + v.y * v.y + v.z * v.z + v.w * v.w;
  #pragma unroll
  for (int m = 1; m < 64; m <<= 1) ss += __shfl_xor(ss, m, 64);
  float inv = 1.0f / sqrtf(ss);
  ushort4 o;
  o.x = f2bf(v.x * inv);
  o.y = f2bf(v.y * inv);
  o.z = f2bf(v.z * inv);
  o.w = f2bf(v.w * inv);
  *reinterpret_cast<ushort4*>(ebf + (size_t)row * DK + lane * 4) = o;
}

// ---------------- Kernel 2: multi-tile blocks; A-panel in registers,
// B-panel staged whole per tile (64 KB LDS), 2 barriers/tile.
__global__ __launch_bounds__(256, 1) void circle_gemm(
    const unsigned short* __restrict__ ebf, const int* __restrict__ labels,
    float* __restrict__ partial) {
  __shared__ unsigned short Bs[BM * DK];            // 64 KB, swizzled storage
  __shared__ float wsum[4];

  int b = blockIdx.x;
  int bid = (b & 7) * (GRID / 8) + (b >> 3);        // XCD swizzle (512 = 8*64)
  int start = (bid * NBLK) / GRID;
  int end = ((bid + 1) * NBLK) / GRID;

  int tid = threadIdx.x;
  int lane = tid & 63;
  int wave = tid >> 6;
  int wr = (wave >> 1) * 64;                        // wave's 64x64 sub-tile
  int wc = (wave & 1) * 64;
  int frow = lane & 15;
  int khi8 = (lane >> 4) * 8;
  int swz = (frow & 7) << 4;

  // decode flat triangular index -> (tr, tc)
  int rem = start, tr = 0;
  while (rem >= NTILE - tr) { rem -= NTILE - tr; ++tr; }
  int tc = tr + rem;

  bf16x8 a[4][8];                                   // A panel frags: 128 VGPR
  int labR[16];

  auto loadA = [&](int trr) {
    int row0 = trr * BM;
    #pragma unroll
    for (int m = 0; m < 4; ++m) {
      const unsigned short* arow =
          ebf + (size_t)(row0 + wr + m * 16 + frow) * DK + khi8;
      #pragma unroll
      for (int s = 0; s < 8; ++s)
        a[m][s] = *reinterpret_cast<const bf16x8*>(arow + s * 32);
    }
    int rbase = row0 + wr + ((lane >> 4) << 2);
    #pragma unroll
    for (int m = 0; m < 4; ++m)
      #pragma unroll
      for (int e = 0; e < 4; ++e)
        labR[m * 4 + e] = labels[rbase + m * 16 + e];
  };

  // stage whole B panel (128 rows x 256 k bf16 = 64 KB); LDS dest linear,
  // global source pre-swizzled so reads can XOR-swizzle (m173 pattern)
  auto stageB = [&](int tcc) {
    int col0 = tcc * BM;
    #pragma unroll
    for (int q = 0; q < 16; ++q) {
      int o = q * 4096 + tid * 16;                  // linear byte offset
      int r = o >> 9;                               // row (512 B rows)
      int os = o ^ ((r & 7) << 4);                  // swizzle within 128B window
      int kc = (os & 511) >> 1;                     // bf16 col within row
      gld_lds16(&ebf[(size_t)(col0 + r) * DK + kc], ((char*)Bs) + o);
    }
  };

  loadA(tr);                                        // prologue
  stageB(tc);

  float lsum = 0.0f;

  for (int t = start; t < end; ++t) {
    int labC[4];
    int cb = tc * BM + wc + frow;
    #pragma unroll
    for (int n = 0; n < 4; ++n) labC[n] = labels[cb + n * 16];

    __syncthreads();                                // stage drained; B ready

    f32x4 accf[4][4] = {};
    #pragma unroll
    for (int s = 0; s < 8; ++s) {
      bf16x8 bfr[4];
      #pragma unroll
      for (int n = 0; n < 4; ++n) {
        int ob = (((wc + n * 16 + frow) << 9) + ((s * 32 + khi8) << 1)) ^ swz;
        bfr[n] = *reinterpret_cast<bf16x8*>(((char*)Bs) + ob);
      }
      #pragma unroll
      for (int m = 0; m < 4; ++m)
        #pragma unroll
        for (int n = 0; n < 4; ++n)
          accf[m][n] = __builtin_amdgcn_mfma_f32_16x16x32_bf16(
              a[m][s], bfr[n], accf[m][n], 0, 0, 0);
    }

    __syncthreads();                                // all waves done reading Bs

    int ntr = tr, ntc = tc + 1;                     // next tile
    if (ntc == NTILE) { ++ntr; ntc = ntr; }
    if (t + 1 < end) stageB(ntc);                   // drain hides under epilogue

    // epilogue: circle-loss terms; C/D layout col=lane&15, row=(lane>>4)*4+reg
    float tsum = 0.0f;
    #pragma unroll
    for (int m = 0; m < 4; ++m) {
      #pragma unroll
      for (int n = 0; n < 4; ++n) {
        #pragma unroll
        for (int e = 0; e < 4; ++e) {
          float sv = accf[m][n][e];
          bool pos = (labR[m * 4 + e] == labC[n]);
          float relu = pos ? fmaxf(sv - 0.75f, 0.0f) : fmaxf(0.25f - sv, 0.0f);
          float arg  = pos ? (2.5f - 2.0f * sv)      : (2.0f * sv + 0.5f);
          tsum += relu * __expf(arg);
        }
      }
    }
    lsum += (tc != tr) ? 2.0f * tsum : tsum;        // symmetry doubling

    if (t + 1 < end && ntr != tr) loadA(ntr);       // after epilogue (labR WAR)
    tr = ntr; tc = ntc;
  }

  #pragma unroll
  for (int m = 32; m; m >>= 1) lsum += __shfl_xor(lsum, m, 64);
  if (lane == 0) wsum[wave] = lsum;
  __syncthreads();
  if (tid == 0) partial[bid] = wsum[0] + wsum[1] + wsum[2] + wsum[3];
}

// ---------------- Kernel 3: reduce partials + log1p (one block)
__global__ __launch_bounds__(256) void finalize_kernel(
    const float* __restrict__ partial, float* __restrict__ out) {
  __shared__ float wsum[4];
  int tid = threadIdx.x;
  float s = partial[tid] + partial[tid + 256];      // GRID = 512
  #pragma unroll
  for (int m = 32; m; m >>= 1) s += __shfl_xor(s, m, 64);
  if ((tid & 63) == 0) wsum[tid >> 6] = s;
  __syncthreads();
  if (tid == 0) out[0] = logf(1.0f + wsum[0] + wsum[1] + wsum[2] + wsum[3]);
}

extern "C" void kernel_launch(void* const* d_in, const int* in_sizes, int n_in,
                              void* d_out, int out_size, void* d_ws, size_t ws_size,
                              hipStream_t stream) {
  const float* emb = (const float*)d_in[0];
  const int* labels = (const int*)d_in[1];
  float* out = (float*)d_out;
  unsigned short* ebf = (unsigned short*)d_ws;                       // 4 MB bf16 E
  float* partial = (float*)((char*)d_ws + (size_t)NB * DK * 2);      // GRID floats

  hipLaunchKernelGGL(normalize_kernel, dim3(NB / 4), dim3(256), 0, stream, emb, ebf);
  hipLaunchKernelGGL(circle_gemm, dim3(GRID), dim3(256), 0, stream, ebf, labels, partial);
  hipLaunchKernelGGL(finalize_kernel, dim3(1), dim3(256), 0, stream, partial, out);
}